// Round 1
// baseline (841.843 us; speedup 1.0000x reference)
//
#include <hip/hip_runtime.h>
#include <math.h>

#define HID 512
#define TW 32   // 2N
#define NQ 16

// ---------------- K1: z1 = x@W1+b1 -> s1, h1 ----------------
__global__ __launch_bounds__(512) void k1_fwd(const float* __restrict__ x,
        const float* __restrict__ W1, const float* __restrict__ b1,
        float* __restrict__ s1g, float* __restrict__ h1g) {
    __shared__ float xr[TW];
    const int r = blockIdx.x;
    const int t = threadIdx.x;
    if (t < TW) xr[t] = x[r * TW + t];
    __syncthreads();
    float z = b1[t];
    #pragma unroll
    for (int k = 0; k < TW; ++k) z = fmaf(xr[k], W1[k * HID + t], z);
    float s = 1.f / (1.f + expf(-z));
    float h = fmaxf(z, 0.f) + log1pf(expf(-fabsf(z)));
    s1g[r * HID + t] = s;
    h1g[r * HID + t] = h;
}

// ---------------- K2: z2 = h1@W2+b2 -> u2 = s2*w3, d2 = s2(1-s2)*w3 ----------------
__global__ __launch_bounds__(256) void k2_z2(const float* __restrict__ h1g,
        const float* __restrict__ W2, const float* __restrict__ b2,
        const float* __restrict__ W3,
        float* __restrict__ u2g, float* __restrict__ d2g) {
    __shared__ float As[16 * 36];
    __shared__ float Bs[16 * 64];
    const int tid = threadIdx.x;
    const int r0 = blockIdx.x * 32;
    const int n0 = blockIdx.y * 64;
    const int tm = tid >> 5;      // 0..7
    const int tn = tid & 31;      // 0..31
    float acc[4][2] = {};
    const int ar = tid >> 3;          // 0..31
    const int ak = (tid & 7) * 2;     // 0..14
    const int bk = tid >> 4;          // 0..15
    const int bn = (tid & 15) * 4;    // 0..60
    for (int k0 = 0; k0 < HID; k0 += 16) {
        __syncthreads();
        float2 av = *(const float2*)&h1g[(r0 + ar) * HID + k0 + ak];
        As[(ak + 0) * 36 + ar] = av.x;
        As[(ak + 1) * 36 + ar] = av.y;
        float4 bv = *(const float4*)&W2[(k0 + bk) * HID + n0 + bn];
        *(float4*)&Bs[bk * 64 + bn] = bv;
        __syncthreads();
        #pragma unroll
        for (int k = 0; k < 16; ++k) {
            float4 a4 = *(const float4*)&As[k * 36 + tm * 4];
            float2 bb = *(const float2*)&Bs[k * 64 + tn * 2];
            acc[0][0] = fmaf(a4.x, bb.x, acc[0][0]);
            acc[0][1] = fmaf(a4.x, bb.y, acc[0][1]);
            acc[1][0] = fmaf(a4.y, bb.x, acc[1][0]);
            acc[1][1] = fmaf(a4.y, bb.y, acc[1][1]);
            acc[2][0] = fmaf(a4.z, bb.x, acc[2][0]);
            acc[2][1] = fmaf(a4.z, bb.y, acc[2][1]);
            acc[3][0] = fmaf(a4.w, bb.x, acc[3][0]);
            acc[3][1] = fmaf(a4.w, bb.y, acc[3][1]);
        }
    }
    #pragma unroll
    for (int q = 0; q < 4; ++q) {
        #pragma unroll
        for (int p = 0; p < 2; ++p) {
            int rr = r0 + tm * 4 + q;
            int nn = n0 + tn * 2 + p;
            float z = acc[q][p] + b2[nn];
            float s = 1.f / (1.f + expf(-z));
            float w3v = W3[nn];
            u2g[rr * HID + nn] = s * w3v;
            d2g[rr * HID + nn] = s * (1.f - s) * w3v;
        }
    }
}

// ---------------- K3: v = u2 @ W2^T ----------------
__global__ __launch_bounds__(256) void k3_v(const float* __restrict__ u2g,
        const float* __restrict__ W2, float* __restrict__ vg) {
    __shared__ float As[16 * 36];
    __shared__ float Bs[16 * 68];
    const int tid = threadIdx.x;
    const int r0 = blockIdx.x * 32;
    const int n0 = blockIdx.y * 64;
    const int tm = tid >> 5;
    const int tn = tid & 31;
    float acc[4][2] = {};
    const int ar = tid >> 3;
    const int ak = (tid & 7) * 2;
    const int ba = tid >> 2;          // 0..63
    const int bb0 = (tid & 3) * 4;    // 0,4,8,12
    for (int k0 = 0; k0 < HID; k0 += 16) {
        __syncthreads();
        float2 av = *(const float2*)&u2g[(r0 + ar) * HID + k0 + ak];
        As[(ak + 0) * 36 + ar] = av.x;
        As[(ak + 1) * 36 + ar] = av.y;
        float4 bv = *(const float4*)&W2[(n0 + ba) * HID + k0 + bb0];
        Bs[(bb0 + 0) * 68 + ba] = bv.x;
        Bs[(bb0 + 1) * 68 + ba] = bv.y;
        Bs[(bb0 + 2) * 68 + ba] = bv.z;
        Bs[(bb0 + 3) * 68 + ba] = bv.w;
        __syncthreads();
        #pragma unroll
        for (int k = 0; k < 16; ++k) {
            float4 a4 = *(const float4*)&As[k * 36 + tm * 4];
            float2 bb = *(const float2*)&Bs[k * 68 + tn * 2];
            acc[0][0] = fmaf(a4.x, bb.x, acc[0][0]);
            acc[0][1] = fmaf(a4.x, bb.y, acc[0][1]);
            acc[1][0] = fmaf(a4.y, bb.x, acc[1][0]);
            acc[1][1] = fmaf(a4.y, bb.y, acc[1][1]);
            acc[2][0] = fmaf(a4.z, bb.x, acc[2][0]);
            acc[2][1] = fmaf(a4.z, bb.y, acc[2][1]);
            acc[3][0] = fmaf(a4.w, bb.x, acc[3][0]);
            acc[3][1] = fmaf(a4.w, bb.y, acc[3][1]);
        }
    }
    #pragma unroll
    for (int q = 0; q < 4; ++q) {
        #pragma unroll
        for (int p = 0; p < 2; ++p) {
            vg[(r0 + tm * 4 + q) * HID + n0 + tn * 2 + p] = acc[q][p];
        }
    }
}

// ---------------- K4: per-row P, H-block, g, solve ----------------
// LDS layout (floats). PB (32 x 1036) aliases/extends the W1S staging area.
#define PB_STRIDE 1036
#define OFF_PB   0
#define OFF_SV   33152
#define OFF_DV   (OFF_SV + 512)
#define OFF_VV   (OFF_DV + 512)
#define OFF_E1   (OFF_VV + 512)
#define OFF_WX   (OFF_E1 + 512)    // 1024
#define OFF_HB   (OFF_WX + 1024)   // 512
#define OFF_GQ   (OFF_HB + 512)    // 32
#define OFF_XR   (OFF_GQ + 32)     // 32
#define OFF_RS   (OFF_XR + 32)     // 16
#define OFF_MU   (OFF_RS + 16)     // 16
#define OFF_QD   (OFF_MU + 16)     // 16
#define OFF_PIV  (OFF_QD + 16)     // 4
#define SMEM_FLOATS (OFF_PIV + 4)  // 36852 floats = 147408 B

__global__ __launch_bounds__(512) void k4_main(
        const float* __restrict__ x, const float* __restrict__ W1,
        const float* __restrict__ W2,
        const float* __restrict__ s1g, const float* __restrict__ d2g,
        const float* __restrict__ vg, float* __restrict__ out) {
    __shared__ float sm[SMEM_FLOATS];
    const int tid = threadIdx.x;
    const int r = blockIdx.x;
    float* W1S = sm;            // 512 x 32 swizzled, aliases PB front
    float* PB  = sm + OFF_PB;   // 32 x PB_STRIDE
    float* SV  = sm + OFF_SV;
    float* DV  = sm + OFF_DV;
    float* VV  = sm + OFF_VV;
    float* E1  = sm + OFF_E1;
    float* WX  = sm + OFF_WX;
    float* HB  = sm + OFF_HB;
    float* GQ  = sm + OFF_GQ;
    float* XR  = sm + OFF_XR;
    float* RS  = sm + OFF_RS;
    float* MU  = sm + OFF_MU;
    float* QD  = sm + OFF_QD;
    int*   PIV = (int*)(sm + OFF_PIV);

    // ph0: per-row vectors
    const float s1t = s1g[r * HID + tid];
    {
        float d = d2g[r * HID + tid];
        float v = vg[r * HID + tid];
        SV[tid] = s1t; DV[tid] = d; VV[tid] = v;
        E1[tid] = s1t * (1.f - s1t) * v;         // d1
        if (tid < TW) XR[tid] = x[r * TW + tid];
    }
    // ph1: W1S[c][j] = W1[j,c]*s1[c], XOR-swizzled groups (c = tid)
    #pragma unroll
    for (int it = 0; it < 32; ++it) {
        float w = W1[it * HID + tid] * s1t;
        int addr = tid * 32 + ((((it >> 2) ^ (tid & 7))) << 2) + (it & 3);
        W1S[addr] = w;
    }
    __syncthreads();

    // ph2: P column b=tid : acc[j] = sum_c W1s[c][j]*W2[c][b]
    float acc[32];
    #pragma unroll
    for (int j = 0; j < 32; ++j) acc[j] = 0.f;
    {
        const float* w2p = W2 + tid;
        for (int c8 = 0; c8 < HID; c8 += 8) {
            float w2v[8];
            #pragma unroll
            for (int k = 0; k < 8; ++k) w2v[k] = w2p[(c8 + k) * HID];
            const float* base = W1S + c8 * 32;
            #pragma unroll
            for (int k = 0; k < 8; ++k) {
                #pragma unroll
                for (int p = 0; p < 8; ++p) {
                    float4 a4 = *(const float4*)(base + k * 32 + p * 4);
                    const int g = ((p ^ k) << 2);
                    acc[g + 0] = fmaf(a4.x, w2v[k], acc[g + 0]);
                    acc[g + 1] = fmaf(a4.y, w2v[k], acc[g + 1]);
                    acc[g + 2] = fmaf(a4.z, w2v[k], acc[g + 2]);
                    acc[g + 3] = fmaf(a4.w, w2v[k], acc[g + 3]);
                }
            }
        }
    }
    // ph3: g_j = sum_a W1s[a][j]*v[a]  (uses W1S before it is overwritten)
    {
        const int j = tid & 31;
        const int seg = tid >> 5;   // 0..15
        const int jg = j >> 2, jl = j & 3;
        float gp = 0.f;
        #pragma unroll
        for (int aa = 0; aa < 32; ++aa) {
            int a = seg * 32 + aa;
            float w = W1S[a * 32 + ((jg ^ (aa & 7)) << 2) + jl];
            gp = fmaf(w, VV[a], gp);
        }
        HB[tid] = gp;   // scratch
    }
    __syncthreads();
    if (tid < 32) {
        float gg = 0.f;
        #pragma unroll
        for (int s2 = 0; s2 < 16; ++s2) gg += HB[s2 * 32 + tid];
        GQ[tid] = gg;
    }
    __syncthreads();   // all W1S reads done

    // ph4: PB[j][b] = P (b<512) or W1[j][b-512]; WX = d2 | d1
    #pragma unroll
    for (int j = 0; j < 32; ++j) PB[j * PB_STRIDE + tid] = acc[j];
    #pragma unroll
    for (int it = 0; it < 32; ++it)
        PB[it * PB_STRIDE + 512 + tid] = W1[it * HID + tid];
    WX[tid] = DV[tid];
    WX[512 + tid] = E1[tid];
    __syncthreads();

    // ph5: H[j][16+i] = sum_b PB[j][b]*WX[b]*PB[16+i][b]
    {
        const int j = tid >> 4;   // 0..31
        const int i = tid & 15;   // 0..15
        const float4* pj = (const float4*)(PB + j * PB_STRIDE);
        const float4* pi = (const float4*)(PB + (16 + i) * PB_STRIDE);
        const float4* wx4 = (const float4*)WX;
        float hh = 0.f;
        #pragma unroll 8
        for (int bq = 0; bq < 256; ++bq) {
            float4 a = pj[bq], b = pi[bq], w = wx4[bq];
            hh = fmaf(a.x * w.x, b.x, hh);
            hh = fmaf(a.y * w.y, b.y, hh);
            hh = fmaf(a.z * w.z, b.z, hh);
            hh = fmaf(a.w * w.w, b.w, hh);
        }
        HB[tid] = hh;  // HB[j*16+i] == HB[tid]
    }
    __syncthreads();

    // rhs = g[:16] - qd @ H[:16,16:]
    if (tid < 16) {
        float t = 0.f;
        #pragma unroll
        for (int m = 0; m < 16; ++m) t = fmaf(XR[16 + m], HB[m * 16 + tid], t);
        RS[tid] = GQ[tid] - t;
    }
    __syncthreads();

    // Gaussian elimination with partial pivoting on A = HB rows 16..31
    float* A = HB + 16 * 16;
    for (int k = 0; k < 16; ++k) {
        if (tid == 0) {
            int p = k; float best = fabsf(A[k * 16 + k]);
            for (int rr = k + 1; rr < 16; ++rr) {
                float vv2 = fabsf(A[rr * 16 + k]);
                if (vv2 > best) { best = vv2; p = rr; }
            }
            PIV[0] = p;
        }
        __syncthreads();
        const int p = PIV[0];
        if (p != k) {
            if (tid < 16) {
                float a1 = A[k * 16 + tid], a2 = A[p * 16 + tid];
                A[k * 16 + tid] = a2; A[p * 16 + tid] = a1;
            } else if (tid == 16) {
                float a1 = RS[k]; RS[k] = RS[p]; RS[p] = a1;
            }
        }
        __syncthreads();
        if (tid > k && tid < 16) MU[tid] = A[tid * 16 + k] / A[k * 16 + k];
        __syncthreads();
        if (tid < 256) {
            int i2 = tid >> 4, j2 = tid & 15;
            if (i2 > k && j2 > k)
                A[i2 * 16 + j2] = fmaf(-MU[i2], A[k * 16 + j2], A[i2 * 16 + j2]);
        } else if (tid < 272) {
            int i2 = tid - 256;
            if (i2 > k) RS[i2] = fmaf(-MU[i2], RS[k], RS[i2]);
        }
        __syncthreads();
    }
    for (int k = 15; k >= 0; --k) {
        if (tid == 0) QD[k] = RS[k] / A[k * 16 + k];
        __syncthreads();
        if (tid < k) RS[tid] = fmaf(-QD[k], A[tid * 16 + k], RS[tid]);
        __syncthreads();
    }

    if (tid < 16) out[r * TW + tid] = XR[16 + tid];
    else if (tid < 32) out[r * TW + tid] = QD[tid - 16];
}

extern "C" void kernel_launch(void* const* d_in, const int* in_sizes, int n_in,
                              void* d_out, int out_size, void* d_ws, size_t ws_size,
                              hipStream_t stream) {
    const float* x  = (const float*)d_in[0];
    const float* W1 = (const float*)d_in[1];
    const float* b1 = (const float*)d_in[2];
    const float* W2 = (const float*)d_in[3];
    const float* b2 = (const float*)d_in[4];
    const float* W3 = (const float*)d_in[5];
    float* out = (float*)d_out;
    float* ws = (float*)d_ws;

    float* s1g = ws;
    float* h1g = ws + (1u << 20);
    float* u2g = ws + 2u * (1u << 20);
    float* d2g = ws + 3u * (1u << 20);
    float* vg  = ws + 4u * (1u << 20);

    k1_fwd<<<2048, 512, 0, stream>>>(x, W1, b1, s1g, h1g);
    dim3 g2(64, 8);
    k2_z2<<<g2, 256, 0, stream>>>(h1g, W2, b2, W3, u2g, d2g);
    k3_v<<<g2, 256, 0, stream>>>(u2g, W2, vg);
    k4_main<<<2048, 512, 0, stream>>>(x, W1, W2, s1g, d2g, vg, out);
}

// Round 2
// 353.034 us; speedup vs baseline: 2.3846x; 2.3846x over previous
//
#include <hip/hip_runtime.h>
#include <math.h>

#define HID 512
#define TW 32
#define NQ 16

// ---------------- K1: z1 = x@W1+b1 -> s1, h1 ----------------
__global__ __launch_bounds__(512) void k1_fwd(const float* __restrict__ x,
        const float* __restrict__ W1, const float* __restrict__ b1,
        float* __restrict__ s1g, float* __restrict__ h1g) {
    __shared__ float xr[TW];
    const int r = blockIdx.x;
    const int t = threadIdx.x;
    if (t < TW) xr[t] = x[r * TW + t];
    __syncthreads();
    float z = b1[t];
    #pragma unroll
    for (int k = 0; k < TW; ++k) z = fmaf(xr[k], W1[k * HID + t], z);
    float s = 1.f / (1.f + expf(-z));
    float h = fmaxf(z, 0.f) + log1pf(expf(-fabsf(z)));
    s1g[r * HID + t] = s;
    h1g[r * HID + t] = h;
}

// ---------------- K2: z2 = h1@W2+b2 -> u2 = s2*w3, d2 = s2(1-s2)*w3 ----------------
__global__ __launch_bounds__(256) void k2_z2(const float* __restrict__ h1g,
        const float* __restrict__ W2, const float* __restrict__ b2,
        const float* __restrict__ W3,
        float* __restrict__ u2g, float* __restrict__ d2g) {
    __shared__ float As[16 * 36];
    __shared__ float Bs[16 * 64];
    const int tid = threadIdx.x;
    const int r0 = blockIdx.x * 32;
    const int n0 = blockIdx.y * 64;
    const int tm = tid >> 5;      // 0..7
    const int tn = tid & 31;      // 0..31
    float acc[4][2] = {};
    const int ar = tid >> 3;          // 0..31
    const int ak = (tid & 7) * 2;     // 0..14
    const int bk = tid >> 4;          // 0..15
    const int bn = (tid & 15) * 4;    // 0..60
    for (int k0 = 0; k0 < HID; k0 += 16) {
        __syncthreads();
        float2 av = *(const float2*)&h1g[(r0 + ar) * HID + k0 + ak];
        As[(ak + 0) * 36 + ar] = av.x;
        As[(ak + 1) * 36 + ar] = av.y;
        float4 bv = *(const float4*)&W2[(k0 + bk) * HID + n0 + bn];
        *(float4*)&Bs[bk * 64 + bn] = bv;
        __syncthreads();
        #pragma unroll
        for (int k = 0; k < 16; ++k) {
            float4 a4 = *(const float4*)&As[k * 36 + tm * 4];
            float2 bb = *(const float2*)&Bs[k * 64 + tn * 2];
            acc[0][0] = fmaf(a4.x, bb.x, acc[0][0]);
            acc[0][1] = fmaf(a4.x, bb.y, acc[0][1]);
            acc[1][0] = fmaf(a4.y, bb.x, acc[1][0]);
            acc[1][1] = fmaf(a4.y, bb.y, acc[1][1]);
            acc[2][0] = fmaf(a4.z, bb.x, acc[2][0]);
            acc[2][1] = fmaf(a4.z, bb.y, acc[2][1]);
            acc[3][0] = fmaf(a4.w, bb.x, acc[3][0]);
            acc[3][1] = fmaf(a4.w, bb.y, acc[3][1]);
        }
    }
    #pragma unroll
    for (int q = 0; q < 4; ++q) {
        #pragma unroll
        for (int p = 0; p < 2; ++p) {
            int rr = r0 + tm * 4 + q;
            int nn = n0 + tn * 2 + p;
            float z = acc[q][p] + b2[nn];
            float s = 1.f / (1.f + expf(-z));
            float w3v = W3[nn];
            u2g[rr * HID + nn] = s * w3v;
            d2g[rr * HID + nn] = s * (1.f - s) * w3v;
        }
    }
}

// ---------------- K3: v = u2 @ W2^T ----------------
__global__ __launch_bounds__(256) void k3_v(const float* __restrict__ u2g,
        const float* __restrict__ W2, float* __restrict__ vg) {
    __shared__ float As[16 * 36];
    __shared__ float Bs[16 * 68];
    const int tid = threadIdx.x;
    const int r0 = blockIdx.x * 32;
    const int n0 = blockIdx.y * 64;
    const int tm = tid >> 5;
    const int tn = tid & 31;
    float acc[4][2] = {};
    const int ar = tid >> 3;
    const int ak = (tid & 7) * 2;
    const int ba = tid >> 2;          // 0..63
    const int bb0 = (tid & 3) * 4;    // 0,4,8,12
    for (int k0 = 0; k0 < HID; k0 += 16) {
        __syncthreads();
        float2 av = *(const float2*)&u2g[(r0 + ar) * HID + k0 + ak];
        As[(ak + 0) * 36 + ar] = av.x;
        As[(ak + 1) * 36 + ar] = av.y;
        float4 bv = *(const float4*)&W2[(n0 + ba) * HID + k0 + bb0];
        Bs[(bb0 + 0) * 68 + ba] = bv.x;
        Bs[(bb0 + 1) * 68 + ba] = bv.y;
        Bs[(bb0 + 2) * 68 + ba] = bv.z;
        Bs[(bb0 + 3) * 68 + ba] = bv.w;
        __syncthreads();
        #pragma unroll
        for (int k = 0; k < 16; ++k) {
            float4 a4 = *(const float4*)&As[k * 36 + tm * 4];
            float2 bb = *(const float2*)&Bs[k * 68 + tn * 2];
            acc[0][0] = fmaf(a4.x, bb.x, acc[0][0]);
            acc[0][1] = fmaf(a4.x, bb.y, acc[0][1]);
            acc[1][0] = fmaf(a4.y, bb.x, acc[1][0]);
            acc[1][1] = fmaf(a4.y, bb.y, acc[1][1]);
            acc[2][0] = fmaf(a4.z, bb.x, acc[2][0]);
            acc[2][1] = fmaf(a4.z, bb.y, acc[2][1]);
            acc[3][0] = fmaf(a4.w, bb.x, acc[3][0]);
            acc[3][1] = fmaf(a4.w, bb.y, acc[3][1]);
        }
    }
    #pragma unroll
    for (int q = 0; q < 4; ++q) {
        #pragma unroll
        for (int p = 0; p < 2; ++p) {
            vg[(r0 + tm * 4 + q) * HID + n0 + tn * 2 + p] = acc[q][p];
        }
    }
}

// ---------------- K4: 4 rows/block; P2 (16 rows), y-vec, H22, T, solve ----------------
#define W1T_STRIDE 36
#define PT_STRIDE  20
#define OFF_W1T 0          // 512*36 = 18432
#define OFF_PT  18432      // 512*20 = 10240 (aliases SVV during g-phase)
#define OFF_SVV OFF_PT     // 512*4 = 2048, dead before PT first written
#define OFF_SU  28672      // 512*8: [c][0..3]=s1 rows, [c][4..7]=u rows
#define OFF_WX  32768      // 1024: [d2 | d1]
#define OFF_YW  33792      // 1024: [y*d2 | qw*d1]
#define OFF_HP  34816      // 8*256
#define OFF_TP  36864      // 32*16
#define OFF_G16 37376      // 4*16
#define OFF_GP  37440      // 512
#define OFF_H2B 37952      // 4*272 (16x17)
#define OFF_RSB 39040      // 4*16
#define OFF_XR  39104      // 4*32
#define OFF_MU  39232      // 4*16
#define OFF_QD  39296      // 4*16
#define OFF_PIV 39360      // 4
#define SMEM_FLOATS 39364  // 157456 B

#define ACC16(rr, t)                                   \
  acc[rr][ 0]=fmaf(a0.x,t,acc[rr][ 0]);                \
  acc[rr][ 1]=fmaf(a0.y,t,acc[rr][ 1]);                \
  acc[rr][ 2]=fmaf(a0.z,t,acc[rr][ 2]);                \
  acc[rr][ 3]=fmaf(a0.w,t,acc[rr][ 3]);                \
  acc[rr][ 4]=fmaf(a1.x,t,acc[rr][ 4]);                \
  acc[rr][ 5]=fmaf(a1.y,t,acc[rr][ 5]);                \
  acc[rr][ 6]=fmaf(a1.z,t,acc[rr][ 6]);                \
  acc[rr][ 7]=fmaf(a1.w,t,acc[rr][ 7]);                \
  acc[rr][ 8]=fmaf(a2.x,t,acc[rr][ 8]);                \
  acc[rr][ 9]=fmaf(a2.y,t,acc[rr][ 9]);                \
  acc[rr][10]=fmaf(a2.z,t,acc[rr][10]);                \
  acc[rr][11]=fmaf(a2.w,t,acc[rr][11]);                \
  acc[rr][12]=fmaf(a3.x,t,acc[rr][12]);                \
  acc[rr][13]=fmaf(a3.y,t,acc[rr][13]);                \
  acc[rr][14]=fmaf(a3.z,t,acc[rr][14]);                \
  acc[rr][15]=fmaf(a3.w,t,acc[rr][15]);

#define HP16(L, p0, p1, p2, p3)                                              \
  hp[0][0]=fmaf(L.x,p0,hp[0][0]); hp[0][1]=fmaf(L.x,p1,hp[0][1]);            \
  hp[0][2]=fmaf(L.x,p2,hp[0][2]); hp[0][3]=fmaf(L.x,p3,hp[0][3]);            \
  hp[1][0]=fmaf(L.y,p0,hp[1][0]); hp[1][1]=fmaf(L.y,p1,hp[1][1]);            \
  hp[1][2]=fmaf(L.y,p2,hp[1][2]); hp[1][3]=fmaf(L.y,p3,hp[1][3]);            \
  hp[2][0]=fmaf(L.z,p0,hp[2][0]); hp[2][1]=fmaf(L.z,p1,hp[2][1]);            \
  hp[2][2]=fmaf(L.z,p2,hp[2][2]); hp[2][3]=fmaf(L.z,p3,hp[2][3]);            \
  hp[3][0]=fmaf(L.w,p0,hp[3][0]); hp[3][1]=fmaf(L.w,p1,hp[3][1]);            \
  hp[3][2]=fmaf(L.w,p2,hp[3][2]); hp[3][3]=fmaf(L.w,p3,hp[3][3]);

__global__ __launch_bounds__(512) void k4_main(
        const float* __restrict__ x, const float* __restrict__ W1,
        const float* __restrict__ W2,
        const float* __restrict__ s1g, const float* __restrict__ d2g,
        const float* __restrict__ vg, float* __restrict__ out) {
    __shared__ __align__(16) float sm[SMEM_FLOATS];
    const int tid = threadIdx.x;
    const int r0 = blockIdx.x * 4;
    float* W1T = sm + OFF_W1T;
    float* PT  = sm + OFF_PT;
    float* SVV = sm + OFF_SVV;
    float* SU  = sm + OFF_SU;
    float* WX  = sm + OFF_WX;
    float* YW  = sm + OFF_YW;
    float* HP  = sm + OFF_HP;
    float* TP  = sm + OFF_TP;
    float* G16 = sm + OFF_G16;
    float* GP  = sm + OFF_GP;
    float* H2B = sm + OFF_H2B;
    float* RSB = sm + OFF_RSB;
    float* XR  = sm + OFF_XR;
    float* MU  = sm + OFF_MU;
    float* QD  = sm + OFF_QD;
    int*   PIV = (int*)(sm + OFF_PIV);

    // ---- ph0: stage W1T (unscaled, shared by 4 rows), s1, s1*v, x rows ----
    #pragma unroll
    for (int q = 0; q < 8; ++q) {
        float4 w;
        w.x = W1[(q*4+0)*HID + tid];
        w.y = W1[(q*4+1)*HID + tid];
        w.z = W1[(q*4+2)*HID + tid];
        w.w = W1[(q*4+3)*HID + tid];
        *(float4*)&W1T[tid*W1T_STRIDE + q*4] = w;
    }
    #pragma unroll
    for (int rr = 0; rr < 4; ++rr) {
        float s1v = s1g[(r0+rr)*HID + tid];
        float vv  = vg[(r0+rr)*HID + tid];
        SU[tid*8 + rr] = s1v;
        SVV[tid*4 + rr] = s1v * vv;
    }
    if (tid < 128) XR[tid] = x[(r0 + (tid>>5))*TW + (tid&31)];
    __syncthreads();

    // ---- ph0b: qw_r[c=tid] = sum_m qd_r[m] W1[m][c]; u = s1*qw ----
    float qw[4];
    {
        float4 wq0 = *(const float4*)&W1T[tid*W1T_STRIDE + 0];
        float4 wq1 = *(const float4*)&W1T[tid*W1T_STRIDE + 4];
        float4 wq2 = *(const float4*)&W1T[tid*W1T_STRIDE + 8];
        float4 wq3 = *(const float4*)&W1T[tid*W1T_STRIDE + 12];
        #pragma unroll
        for (int rr = 0; rr < 4; ++rr) {
            float4 q0 = *(const float4*)&XR[rr*TW + 16];
            float4 q1 = *(const float4*)&XR[rr*TW + 20];
            float4 q2 = *(const float4*)&XR[rr*TW + 24];
            float4 q3 = *(const float4*)&XR[rr*TW + 28];
            float s = 0.f;
            s = fmaf(q0.x, wq0.x, s); s = fmaf(q0.y, wq0.y, s);
            s = fmaf(q0.z, wq0.z, s); s = fmaf(q0.w, wq0.w, s);
            s = fmaf(q1.x, wq1.x, s); s = fmaf(q1.y, wq1.y, s);
            s = fmaf(q1.z, wq1.z, s); s = fmaf(q1.w, wq1.w, s);
            s = fmaf(q2.x, wq2.x, s); s = fmaf(q2.y, wq2.y, s);
            s = fmaf(q2.z, wq2.z, s); s = fmaf(q2.w, wq2.w, s);
            s = fmaf(q3.x, wq3.x, s); s = fmaf(q3.y, wq3.y, s);
            s = fmaf(q3.z, wq3.z, s); s = fmaf(q3.w, wq3.w, s);
            qw[rr] = s;
            SU[tid*8 + 4 + rr] = SU[tid*8 + rr] * s;
        }
    }

    // ---- ph1: g16 partials: g_j = sum_c W1[j][c] * s1[c] * v[c], j<16 ----
    {
        const int rr  = tid >> 7;
        const int j   = (tid >> 3) & 15;
        const int seg = tid & 7;
        float gp = 0.f;
        #pragma unroll 8
        for (int it = 0; it < 64; ++it) {
            int c = it*8 + seg;
            gp = fmaf(W1T[c*W1T_STRIDE + j], SVV[c*4 + rr], gp);
        }
        GP[tid] = gp;
    }
    __syncthreads();
    if (tid < 64) {
        float g = 0.f;
        #pragma unroll
        for (int s = 0; s < 8; ++s) g += GP[tid*8 + s];
        G16[tid] = g;
    }

    // ---- ph2': P2 columns + y vector, 4 rows at once ----
    float acc[4][16];
    float yv[4] = {0.f, 0.f, 0.f, 0.f};
    #pragma unroll
    for (int rr = 0; rr < 4; ++rr)
        #pragma unroll
        for (int i = 0; i < 16; ++i) acc[rr][i] = 0.f;
    {
        const float* w2p = W2 + tid;
        #pragma unroll 1
        for (int c8 = 0; c8 < HID; c8 += 8) {
            float w2v[8];
            #pragma unroll
            for (int k = 0; k < 8; ++k) w2v[k] = w2p[(c8+k)*HID];
            #pragma unroll
            for (int k = 0; k < 8; ++k) {
                const int c = c8 + k;
                float4 s4 = *(const float4*)&SU[c*8];
                float4 u4 = *(const float4*)&SU[c*8 + 4];
                float4 a0 = *(const float4*)&W1T[c*W1T_STRIDE + 16];
                float4 a1 = *(const float4*)&W1T[c*W1T_STRIDE + 20];
                float4 a2 = *(const float4*)&W1T[c*W1T_STRIDE + 24];
                float4 a3 = *(const float4*)&W1T[c*W1T_STRIDE + 28];
                const float w2 = w2v[k];
                yv[0] = fmaf(u4.x, w2, yv[0]);
                yv[1] = fmaf(u4.y, w2, yv[1]);
                yv[2] = fmaf(u4.z, w2, yv[2]);
                yv[3] = fmaf(u4.w, w2, yv[3]);
                float t0 = s4.x * w2;
                float t1 = s4.y * w2;
                float t2 = s4.z * w2;
                float t3 = s4.w * w2;
                ACC16(0, t0)
                ACC16(1, t1)
                ACC16(2, t2)
                ACC16(3, t3)
            }
        }
    }

    // ---- ph5: per row: stage PT/WX/YW, H22 pass, T pass, reduce ----
    const int seg5 = tid >> 4;        // 0..31
    const int iq5  = (tid >> 2) & 3;
    const int eq5  = tid & 3;
    const int i35  = tid & 15;
    const int lane = tid & 63;
    const int wv   = tid >> 6;
    #pragma unroll
    for (int rr = 0; rr < 4; ++rr) {
        __syncthreads();
        {
            float d2v = d2g[(r0+rr)*HID + tid];
            float vv  = vg[(r0+rr)*HID + tid];
            float s1v = SU[tid*8 + rr];
            float e1v = s1v * (1.f - s1v) * vv;
            WX[tid] = d2v;
            WX[512 + tid] = e1v;
            YW[tid] = yv[rr] * d2v;
            YW[512 + tid] = qw[rr] * e1v;
            *(float4*)&PT[tid*PT_STRIDE +  0] = make_float4(acc[rr][ 0], acc[rr][ 1], acc[rr][ 2], acc[rr][ 3]);
            *(float4*)&PT[tid*PT_STRIDE +  4] = make_float4(acc[rr][ 4], acc[rr][ 5], acc[rr][ 6], acc[rr][ 7]);
            *(float4*)&PT[tid*PT_STRIDE +  8] = make_float4(acc[rr][ 8], acc[rr][ 9], acc[rr][10], acc[rr][11]);
            *(float4*)&PT[tid*PT_STRIDE + 12] = make_float4(acc[rr][12], acc[rr][13], acc[rr][14], acc[rr][15]);
        }
        __syncthreads();
        // H22 pass: O[iq5*4+d][eq5*4+e] partial over b = it*32+seg5
        float hp[4][4] = {};
        #pragma unroll 4
        for (int it = 0; it < 16; ++it) {
            int b = it*32 + seg5;
            float4 L = *(const float4*)&PT[b*PT_STRIDE + iq5*4];
            float4 R = *(const float4*)&PT[b*PT_STRIDE + eq5*4];
            float w = WX[b];
            float p0 = R.x*w, p1 = R.y*w, p2 = R.z*w, p3 = R.w*w;
            HP16(L, p0, p1, p2, p3)
        }
        #pragma unroll 4
        for (int it = 0; it < 16; ++it) {
            int a = it*32 + seg5;
            float4 L = *(const float4*)&W1T[a*W1T_STRIDE + 16 + iq5*4];
            float4 R = *(const float4*)&W1T[a*W1T_STRIDE + 16 + eq5*4];
            float w = WX[512 + a];
            float p0 = R.x*w, p1 = R.y*w, p2 = R.z*w, p3 = R.w*w;
            HP16(L, p0, p1, p2, p3)
        }
        #pragma unroll
        for (int d = 0; d < 4; ++d)
            #pragma unroll
            for (int e = 0; e < 4; ++e) {
                float v2 = hp[d][e];
                v2 += __shfl_down(v2, 32);
                v2 += __shfl_down(v2, 16);
                hp[d][e] = v2;
            }
        if (lane < 16) {
            #pragma unroll
            for (int d = 0; d < 4; ++d)
                #pragma unroll
                for (int e = 0; e < 4; ++e)
                    HP[wv*256 + (iq5*4+d)*16 + (eq5*4+e)] = hp[d][e];
        }
        // T pass: T[i35] partial over b = it*32+seg5
        {
            float tp = 0.f;
            #pragma unroll 4
            for (int it = 0; it < 16; ++it) {
                int b = it*32 + seg5;
                tp = fmaf(YW[b], PT[b*PT_STRIDE + i35], tp);
            }
            #pragma unroll 4
            for (int it = 0; it < 16; ++it) {
                int a = it*32 + seg5;
                tp = fmaf(YW[512 + a], W1T[a*W1T_STRIDE + 16 + i35], tp);
            }
            TP[tid & 511] = tp;
        }
        __syncthreads();
        if (tid < 256) {
            float s = 0.f;
            #pragma unroll
            for (int w8 = 0; w8 < 8; ++w8) s += HP[w8*256 + tid];
            H2B[rr*272 + (tid>>4)*17 + (tid&15)] = s;
        } else if (tid < 272) {
            const int i3 = tid - 256;
            float t = 0.f;
            #pragma unroll
            for (int s2 = 0; s2 < 32; ++s2) t += TP[s2*16 + i3];
            RSB[rr*16 + i3] = G16[rr*16 + i3] - t;
        }
    }
    __syncthreads();

    // ---- solve: 4 parallel 16x16 Gaussian eliminations w/ partial pivot ----
    {
        const int row = tid >> 7;
        const int lt = tid & 127;
        float* A = H2B + row*272;
        float* rs = RSB + row*16;
        for (int k = 0; k < 16; ++k) {
            if (lt == 0) {
                int p = k; float best = fabsf(A[k*17+k]);
                for (int r2 = k+1; r2 < 16; ++r2) {
                    float v2 = fabsf(A[r2*17+k]);
                    if (v2 > best) { best = v2; p = r2; }
                }
                PIV[row] = p;
            }
            __syncthreads();
            const int p = PIV[row];
            if (p != k) {
                if (lt < 16) {
                    float t1 = A[k*17+lt]; A[k*17+lt] = A[p*17+lt]; A[p*17+lt] = t1;
                } else if (lt == 16) {
                    float t1 = rs[k]; rs[k] = rs[p]; rs[p] = t1;
                }
            }
            __syncthreads();
            if (lt > k && lt < 16) MU[row*16+lt] = A[lt*17+k] / A[k*17+k];
            __syncthreads();
            {
                const int i2 = lt >> 3;
                const int j2 = (lt & 7) * 2;
                if (i2 > k) {
                    float mu = MU[row*16+i2];
                    A[i2*17+j2]   = fmaf(-mu, A[k*17+j2],   A[i2*17+j2]);
                    A[i2*17+j2+1] = fmaf(-mu, A[k*17+j2+1], A[i2*17+j2+1]);
                    if ((lt & 7) == 0) rs[i2] = fmaf(-mu, rs[k], rs[i2]);
                }
            }
            __syncthreads();
        }
        for (int k = 15; k >= 0; --k) {
            if (lt == 0) QD[row*16+k] = rs[k] / A[k*17+k];
            __syncthreads();
            if (lt < k) rs[lt] = fmaf(-QD[row*16+k], A[lt*17+k], rs[lt]);
            __syncthreads();
        }
    }

    if (tid < 128) {
        const int row = tid >> 5;
        const int e = tid & 31;
        out[(r0+row)*TW + e] = (e < 16) ? XR[row*TW + 16 + e] : QD[row*16 + e - 16];
    }
}

extern "C" void kernel_launch(void* const* d_in, const int* in_sizes, int n_in,
                              void* d_out, int out_size, void* d_ws, size_t ws_size,
                              hipStream_t stream) {
    const float* x  = (const float*)d_in[0];
    const float* W1 = (const float*)d_in[1];
    const float* b1 = (const float*)d_in[2];
    const float* W2 = (const float*)d_in[3];
    const float* b2 = (const float*)d_in[4];
    const float* W3 = (const float*)d_in[5];
    float* out = (float*)d_out;
    float* ws = (float*)d_ws;

    float* s1g = ws;
    float* h1g = ws + (1u << 20);
    float* u2g = ws + 2u * (1u << 20);
    float* d2g = ws + 3u * (1u << 20);
    float* vg  = ws + 4u * (1u << 20);

    k1_fwd<<<2048, 512, 0, stream>>>(x, W1, b1, s1g, h1g);
    dim3 g2(64, 8);
    k2_z2<<<g2, 256, 0, stream>>>(h1g, W2, b2, W3, u2g, d2g);
    k3_v<<<g2, 256, 0, stream>>>(u2g, W2, vg);
    k4_main<<<512, 512, 0, stream>>>(x, W1, W2, s1g, d2g, vg, out);
}

// Round 3
// 352.922 us; speedup vs baseline: 2.3854x; 1.0003x over previous
//
#include <hip/hip_runtime.h>
#include <math.h>

#define HID 512
#define TW 32
#define NQ 16

// ---------------- K1: z1 = x@W1+b1 -> s1, h1 ----------------
__global__ __launch_bounds__(512) void k1_fwd(const float* __restrict__ x,
        const float* __restrict__ W1, const float* __restrict__ b1,
        float* __restrict__ s1g, float* __restrict__ h1g) {
    __shared__ float xr[TW];
    const int r = blockIdx.x;
    const int t = threadIdx.x;
    if (t < TW) xr[t] = x[r * TW + t];
    __syncthreads();
    float z = b1[t];
    #pragma unroll
    for (int k = 0; k < TW; ++k) z = fmaf(xr[k], W1[k * HID + t], z);
    float s = 1.f / (1.f + expf(-z));
    float h = fmaxf(z, 0.f) + log1pf(expf(-fabsf(z)));
    s1g[r * HID + t] = s;
    h1g[r * HID + t] = h;
}

// ---------------- K2: z2 = h1@W2+b2 -> u2 = s2*w3, d2 = s2(1-s2)*w3 ----------------
__global__ __launch_bounds__(256) void k2_z2(const float* __restrict__ h1g,
        const float* __restrict__ W2, const float* __restrict__ b2,
        const float* __restrict__ W3,
        float* __restrict__ u2g, float* __restrict__ d2g) {
    __shared__ float As[16 * 36];
    __shared__ float Bs[16 * 64];
    const int tid = threadIdx.x;
    const int r0 = blockIdx.x * 32;
    const int n0 = blockIdx.y * 64;
    const int tm = tid >> 5;      // 0..7
    const int tn = tid & 31;      // 0..31
    float acc[4][2] = {};
    const int ar = tid >> 3;          // 0..31
    const int ak = (tid & 7) * 2;     // 0..14
    const int bk = tid >> 4;          // 0..15
    const int bn = (tid & 15) * 4;    // 0..60
    for (int k0 = 0; k0 < HID; k0 += 16) {
        __syncthreads();
        float2 av = *(const float2*)&h1g[(r0 + ar) * HID + k0 + ak];
        As[(ak + 0) * 36 + ar] = av.x;
        As[(ak + 1) * 36 + ar] = av.y;
        float4 bv = *(const float4*)&W2[(k0 + bk) * HID + n0 + bn];
        *(float4*)&Bs[bk * 64 + bn] = bv;
        __syncthreads();
        #pragma unroll
        for (int k = 0; k < 16; ++k) {
            float4 a4 = *(const float4*)&As[k * 36 + tm * 4];
            float2 bb = *(const float2*)&Bs[k * 64 + tn * 2];
            acc[0][0] = fmaf(a4.x, bb.x, acc[0][0]);
            acc[0][1] = fmaf(a4.x, bb.y, acc[0][1]);
            acc[1][0] = fmaf(a4.y, bb.x, acc[1][0]);
            acc[1][1] = fmaf(a4.y, bb.y, acc[1][1]);
            acc[2][0] = fmaf(a4.z, bb.x, acc[2][0]);
            acc[2][1] = fmaf(a4.z, bb.y, acc[2][1]);
            acc[3][0] = fmaf(a4.w, bb.x, acc[3][0]);
            acc[3][1] = fmaf(a4.w, bb.y, acc[3][1]);
        }
    }
    #pragma unroll
    for (int q = 0; q < 4; ++q) {
        #pragma unroll
        for (int p = 0; p < 2; ++p) {
            int rr = r0 + tm * 4 + q;
            int nn = n0 + tn * 2 + p;
            float z = acc[q][p] + b2[nn];
            float s = 1.f / (1.f + expf(-z));
            float w3v = W3[nn];
            u2g[rr * HID + nn] = s * w3v;
            d2g[rr * HID + nn] = s * (1.f - s) * w3v;
        }
    }
}

// ---------------- K3: v = u2 @ W2^T ----------------
__global__ __launch_bounds__(256) void k3_v(const float* __restrict__ u2g,
        const float* __restrict__ W2, float* __restrict__ vg) {
    __shared__ float As[16 * 36];
    __shared__ float Bs[16 * 68];
    const int tid = threadIdx.x;
    const int r0 = blockIdx.x * 32;
    const int n0 = blockIdx.y * 64;
    const int tm = tid >> 5;
    const int tn = tid & 31;
    float acc[4][2] = {};
    const int ar = tid >> 3;
    const int ak = (tid & 7) * 2;
    const int ba = tid >> 2;          // 0..63
    const int bb0 = (tid & 3) * 4;    // 0,4,8,12
    for (int k0 = 0; k0 < HID; k0 += 16) {
        __syncthreads();
        float2 av = *(const float2*)&u2g[(r0 + ar) * HID + k0 + ak];
        As[(ak + 0) * 36 + ar] = av.x;
        As[(ak + 1) * 36 + ar] = av.y;
        float4 bv = *(const float4*)&W2[(n0 + ba) * HID + k0 + bb0];
        Bs[(bb0 + 0) * 68 + ba] = bv.x;
        Bs[(bb0 + 1) * 68 + ba] = bv.y;
        Bs[(bb0 + 2) * 68 + ba] = bv.z;
        Bs[(bb0 + 3) * 68 + ba] = bv.w;
        __syncthreads();
        #pragma unroll
        for (int k = 0; k < 16; ++k) {
            float4 a4 = *(const float4*)&As[k * 36 + tm * 4];
            float2 bb = *(const float2*)&Bs[k * 68 + tn * 2];
            acc[0][0] = fmaf(a4.x, bb.x, acc[0][0]);
            acc[0][1] = fmaf(a4.x, bb.y, acc[0][1]);
            acc[1][0] = fmaf(a4.y, bb.x, acc[1][0]);
            acc[1][1] = fmaf(a4.y, bb.y, acc[1][1]);
            acc[2][0] = fmaf(a4.z, bb.x, acc[2][0]);
            acc[2][1] = fmaf(a4.z, bb.y, acc[2][1]);
            acc[3][0] = fmaf(a4.w, bb.x, acc[3][0]);
            acc[3][1] = fmaf(a4.w, bb.y, acc[3][1]);
        }
    }
    #pragma unroll
    for (int q = 0; q < 4; ++q) {
        #pragma unroll
        for (int p = 0; p < 2; ++p) {
            vg[(r0 + tm * 4 + q) * HID + n0 + tn * 2 + p] = acc[q][p];
        }
    }
}

// ---------------- K4: 4 rows/block; P2 (16 rows), y-vec, H22, T, solve ----------------
#define W1T_STRIDE 36
#define PT_STRIDE  20
#define OFF_W1T 0          // 512*36 = 18432
#define OFF_PT  18432      // 512*20 = 10240 (aliases SVV during g-phase)
#define OFF_SVV OFF_PT     // 512*4 = 2048, dead before PT first written
#define OFF_SU  28672      // 512*8: [c][0..3]=s1 rows, [c][4..7]=u rows
#define OFF_WX  32768      // 1024: [d2 | d1]
#define OFF_YW  33792      // 1024: [y*d2 | qw*d1]
#define OFF_HP  34816      // 8*256
#define OFF_TP  36864      // 32*16
#define OFF_G16 37376      // 4*16
#define OFF_GP  37440      // 512
#define OFF_H2B 37952      // 4*272 (16x17)
#define OFF_RSB 39040      // 4*16
#define OFF_XR  39104      // 4*32
#define OFF_MU  39232      // 4*16
#define OFF_QD  39296      // 4*16
#define OFF_PIV 39360      // 4
#define SMEM_FLOATS 39364  // 157456 B

#define ACC16(rr, t)                                   \
  acc[rr][ 0]=fmaf(a0.x,t,acc[rr][ 0]);                \
  acc[rr][ 1]=fmaf(a0.y,t,acc[rr][ 1]);                \
  acc[rr][ 2]=fmaf(a0.z,t,acc[rr][ 2]);                \
  acc[rr][ 3]=fmaf(a0.w,t,acc[rr][ 3]);                \
  acc[rr][ 4]=fmaf(a1.x,t,acc[rr][ 4]);                \
  acc[rr][ 5]=fmaf(a1.y,t,acc[rr][ 5]);                \
  acc[rr][ 6]=fmaf(a1.z,t,acc[rr][ 6]);                \
  acc[rr][ 7]=fmaf(a1.w,t,acc[rr][ 7]);                \
  acc[rr][ 8]=fmaf(a2.x,t,acc[rr][ 8]);                \
  acc[rr][ 9]=fmaf(a2.y,t,acc[rr][ 9]);                \
  acc[rr][10]=fmaf(a2.z,t,acc[rr][10]);                \
  acc[rr][11]=fmaf(a2.w,t,acc[rr][11]);                \
  acc[rr][12]=fmaf(a3.x,t,acc[rr][12]);                \
  acc[rr][13]=fmaf(a3.y,t,acc[rr][13]);                \
  acc[rr][14]=fmaf(a3.z,t,acc[rr][14]);                \
  acc[rr][15]=fmaf(a3.w,t,acc[rr][15]);

#define HP16(L, p0, p1, p2, p3)                                              \
  hp[0][0]=fmaf(L.x,p0,hp[0][0]); hp[0][1]=fmaf(L.x,p1,hp[0][1]);            \
  hp[0][2]=fmaf(L.x,p2,hp[0][2]); hp[0][3]=fmaf(L.x,p3,hp[0][3]);            \
  hp[1][0]=fmaf(L.y,p0,hp[1][0]); hp[1][1]=fmaf(L.y,p1,hp[1][1]);            \
  hp[1][2]=fmaf(L.y,p2,hp[1][2]); hp[1][3]=fmaf(L.y,p3,hp[1][3]);            \
  hp[2][0]=fmaf(L.z,p0,hp[2][0]); hp[2][1]=fmaf(L.z,p1,hp[2][1]);            \
  hp[2][2]=fmaf(L.z,p2,hp[2][2]); hp[2][3]=fmaf(L.z,p3,hp[2][3]);            \
  hp[3][0]=fmaf(L.w,p0,hp[3][0]); hp[3][1]=fmaf(L.w,p1,hp[3][1]);            \
  hp[3][2]=fmaf(L.w,p2,hp[3][2]); hp[3][3]=fmaf(L.w,p3,hp[3][3]);

__global__ __launch_bounds__(512) void k4_main(
        const float* __restrict__ x, const float* __restrict__ W1,
        const float* __restrict__ W2,
        const float* __restrict__ s1g, const float* __restrict__ d2g,
        const float* __restrict__ vg, float* __restrict__ out) {
    __shared__ __align__(16) float sm[SMEM_FLOATS];
    const int tid = threadIdx.x;
    const int r0 = blockIdx.x * 4;
    float* W1T = sm + OFF_W1T;
    float* PT  = sm + OFF_PT;
    float* SVV = sm + OFF_SVV;
    float* SU  = sm + OFF_SU;
    float* WX  = sm + OFF_WX;
    float* YW  = sm + OFF_YW;
    float* HP  = sm + OFF_HP;
    float* TP  = sm + OFF_TP;
    float* G16 = sm + OFF_G16;
    float* GP  = sm + OFF_GP;
    float* H2B = sm + OFF_H2B;
    float* RSB = sm + OFF_RSB;
    float* XR  = sm + OFF_XR;
    float* MU  = sm + OFF_MU;
    float* QD  = sm + OFF_QD;
    int*   PIV = (int*)(sm + OFF_PIV);

    // ---- ph0: stage W1T (unscaled, shared by 4 rows), s1, s1*v, x rows ----
    #pragma unroll
    for (int q = 0; q < 8; ++q) {
        float4 w;
        w.x = W1[(q*4+0)*HID + tid];
        w.y = W1[(q*4+1)*HID + tid];
        w.z = W1[(q*4+2)*HID + tid];
        w.w = W1[(q*4+3)*HID + tid];
        *(float4*)&W1T[tid*W1T_STRIDE + q*4] = w;
    }
    #pragma unroll
    for (int rr = 0; rr < 4; ++rr) {
        float s1v = s1g[(r0+rr)*HID + tid];
        float vv  = vg[(r0+rr)*HID + tid];
        SU[tid*8 + rr] = s1v;
        SVV[tid*4 + rr] = s1v * vv;
    }
    if (tid < 128) XR[tid] = x[(r0 + (tid>>5))*TW + (tid&31)];
    __syncthreads();

    // ---- ph0b: qw_r[c=tid] = sum_m qd_r[m] W1[m][c]; u = s1*qw ----
    float qw[4];
    {
        float4 wq0 = *(const float4*)&W1T[tid*W1T_STRIDE + 0];
        float4 wq1 = *(const float4*)&W1T[tid*W1T_STRIDE + 4];
        float4 wq2 = *(const float4*)&W1T[tid*W1T_STRIDE + 8];
        float4 wq3 = *(const float4*)&W1T[tid*W1T_STRIDE + 12];
        #pragma unroll
        for (int rr = 0; rr < 4; ++rr) {
            float4 q0 = *(const float4*)&XR[rr*TW + 16];
            float4 q1 = *(const float4*)&XR[rr*TW + 20];
            float4 q2 = *(const float4*)&XR[rr*TW + 24];
            float4 q3 = *(const float4*)&XR[rr*TW + 28];
            float s = 0.f;
            s = fmaf(q0.x, wq0.x, s); s = fmaf(q0.y, wq0.y, s);
            s = fmaf(q0.z, wq0.z, s); s = fmaf(q0.w, wq0.w, s);
            s = fmaf(q1.x, wq1.x, s); s = fmaf(q1.y, wq1.y, s);
            s = fmaf(q1.z, wq1.z, s); s = fmaf(q1.w, wq1.w, s);
            s = fmaf(q2.x, wq2.x, s); s = fmaf(q2.y, wq2.y, s);
            s = fmaf(q2.z, wq2.z, s); s = fmaf(q2.w, wq2.w, s);
            s = fmaf(q3.x, wq3.x, s); s = fmaf(q3.y, wq3.y, s);
            s = fmaf(q3.z, wq3.z, s); s = fmaf(q3.w, wq3.w, s);
            qw[rr] = s;
            SU[tid*8 + 4 + rr] = SU[tid*8 + rr] * s;
        }
    }

    // ---- ph1: g16 partials: g_j = sum_c W1[j][c] * s1[c] * v[c], j<16 ----
    {
        const int rr  = tid >> 7;
        const int j   = (tid >> 3) & 15;
        const int seg = tid & 7;
        float gp = 0.f;
        #pragma unroll 8
        for (int it = 0; it < 64; ++it) {
            int c = it*8 + seg;
            gp = fmaf(W1T[c*W1T_STRIDE + j], SVV[c*4 + rr], gp);
        }
        GP[tid] = gp;
    }
    __syncthreads();
    if (tid < 64) {
        float g = 0.f;
        #pragma unroll
        for (int s = 0; s < 8; ++s) g += GP[tid*8 + s];
        G16[tid] = g;
    }

    // ---- ph2': P2 columns + y vector, 4 rows at once ----
    float acc[4][16];
    float yv[4] = {0.f, 0.f, 0.f, 0.f};
    #pragma unroll
    for (int rr = 0; rr < 4; ++rr)
        #pragma unroll
        for (int i = 0; i < 16; ++i) acc[rr][i] = 0.f;
    {
        const float* w2p = W2 + tid;
        #pragma unroll 1
        for (int c8 = 0; c8 < HID; c8 += 8) {
            float w2v[8];
            #pragma unroll
            for (int k = 0; k < 8; ++k) w2v[k] = w2p[(c8+k)*HID];
            #pragma unroll
            for (int k = 0; k < 8; ++k) {
                const int c = c8 + k;
                float4 s4 = *(const float4*)&SU[c*8];
                float4 u4 = *(const float4*)&SU[c*8 + 4];
                float4 a0 = *(const float4*)&W1T[c*W1T_STRIDE + 16];
                float4 a1 = *(const float4*)&W1T[c*W1T_STRIDE + 20];
                float4 a2 = *(const float4*)&W1T[c*W1T_STRIDE + 24];
                float4 a3 = *(const float4*)&W1T[c*W1T_STRIDE + 28];
                const float w2 = w2v[k];
                yv[0] = fmaf(u4.x, w2, yv[0]);
                yv[1] = fmaf(u4.y, w2, yv[1]);
                yv[2] = fmaf(u4.z, w2, yv[2]);
                yv[3] = fmaf(u4.w, w2, yv[3]);
                float t0 = s4.x * w2;
                float t1 = s4.y * w2;
                float t2 = s4.z * w2;
                float t3 = s4.w * w2;
                ACC16(0, t0)
                ACC16(1, t1)
                ACC16(2, t2)
                ACC16(3, t3)
            }
        }
    }

    // ---- ph5: per row: stage PT/WX/YW, H22 pass, T pass, reduce ----
    const int seg5 = tid >> 4;        // 0..31
    const int iq5  = (tid >> 2) & 3;
    const int eq5  = tid & 3;
    const int i35  = tid & 15;
    const int lane = tid & 63;
    const int wv   = tid >> 6;
    #pragma unroll
    for (int rr = 0; rr < 4; ++rr) {
        __syncthreads();
        {
            float d2v = d2g[(r0+rr)*HID + tid];
            float vv  = vg[(r0+rr)*HID + tid];
            float s1v = SU[tid*8 + rr];
            float e1v = s1v * (1.f - s1v) * vv;
            WX[tid] = d2v;
            WX[512 + tid] = e1v;
            YW[tid] = yv[rr] * d2v;
            YW[512 + tid] = qw[rr] * e1v;
            *(float4*)&PT[tid*PT_STRIDE +  0] = make_float4(acc[rr][ 0], acc[rr][ 1], acc[rr][ 2], acc[rr][ 3]);
            *(float4*)&PT[tid*PT_STRIDE +  4] = make_float4(acc[rr][ 4], acc[rr][ 5], acc[rr][ 6], acc[rr][ 7]);
            *(float4*)&PT[tid*PT_STRIDE +  8] = make_float4(acc[rr][ 8], acc[rr][ 9], acc[rr][10], acc[rr][11]);
            *(float4*)&PT[tid*PT_STRIDE + 12] = make_float4(acc[rr][12], acc[rr][13], acc[rr][14], acc[rr][15]);
        }
        __syncthreads();
        // H22 pass: O[iq5*4+d][eq5*4+e] partial over b = it*32+seg5
        float hp[4][4] = {};
        #pragma unroll 4
        for (int it = 0; it < 16; ++it) {
            int b = it*32 + seg5;
            float4 L = *(const float4*)&PT[b*PT_STRIDE + iq5*4];
            float4 R = *(const float4*)&PT[b*PT_STRIDE + eq5*4];
            float w = WX[b];
            float p0 = R.x*w, p1 = R.y*w, p2 = R.z*w, p3 = R.w*w;
            HP16(L, p0, p1, p2, p3)
        }
        #pragma unroll 4
        for (int it = 0; it < 16; ++it) {
            int a = it*32 + seg5;
            float4 L = *(const float4*)&W1T[a*W1T_STRIDE + 16 + iq5*4];
            float4 R = *(const float4*)&W1T[a*W1T_STRIDE + 16 + eq5*4];
            float w = WX[512 + a];
            float p0 = R.x*w, p1 = R.y*w, p2 = R.z*w, p3 = R.w*w;
            HP16(L, p0, p1, p2, p3)
        }
        #pragma unroll
        for (int d = 0; d < 4; ++d)
            #pragma unroll
            for (int e = 0; e < 4; ++e) {
                float v2 = hp[d][e];
                v2 += __shfl_down(v2, 32);
                v2 += __shfl_down(v2, 16);
                hp[d][e] = v2;
            }
        if (lane < 16) {
            #pragma unroll
            for (int d = 0; d < 4; ++d)
                #pragma unroll
                for (int e = 0; e < 4; ++e)
                    HP[wv*256 + (iq5*4+d)*16 + (eq5*4+e)] = hp[d][e];
        }
        // T pass: T[i35] partial over b = it*32+seg5
        {
            float tp = 0.f;
            #pragma unroll 4
            for (int it = 0; it < 16; ++it) {
                int b = it*32 + seg5;
                tp = fmaf(YW[b], PT[b*PT_STRIDE + i35], tp);
            }
            #pragma unroll 4
            for (int it = 0; it < 16; ++it) {
                int a = it*32 + seg5;
                tp = fmaf(YW[512 + a], W1T[a*W1T_STRIDE + 16 + i35], tp);
            }
            TP[tid & 511] = tp;
        }
        __syncthreads();
        if (tid < 256) {
            float s = 0.f;
            #pragma unroll
            for (int w8 = 0; w8 < 8; ++w8) s += HP[w8*256 + tid];
            H2B[rr*272 + (tid>>4)*17 + (tid&15)] = s;
        } else if (tid < 272) {
            const int i3 = tid - 256;
            float t = 0.f;
            #pragma unroll
            for (int s2 = 0; s2 < 32; ++s2) t += TP[s2*16 + i3];
            RSB[rr*16 + i3] = G16[rr*16 + i3] - t;
        }
    }
    __syncthreads();

    // ---- solve: 4 parallel 16x16 Gaussian eliminations w/ partial pivot ----
    {
        const int row = tid >> 7;
        const int lt = tid & 127;
        float* A = H2B + row*272;
        float* rs = RSB + row*16;
        for (int k = 0; k < 16; ++k) {
            if (lt == 0) {
                int p = k; float best = fabsf(A[k*17+k]);
                for (int r2 = k+1; r2 < 16; ++r2) {
                    float v2 = fabsf(A[r2*17+k]);
                    if (v2 > best) { best = v2; p = r2; }
                }
                PIV[row] = p;
            }
            __syncthreads();
            const int p = PIV[row];
            if (p != k) {
                if (lt < 16) {
                    float t1 = A[k*17+lt]; A[k*17+lt] = A[p*17+lt]; A[p*17+lt] = t1;
                } else if (lt == 16) {
                    float t1 = rs[k]; rs[k] = rs[p]; rs[p] = t1;
                }
            }
            __syncthreads();
            if (lt > k && lt < 16) MU[row*16+lt] = A[lt*17+k] / A[k*17+k];
            __syncthreads();
            {
                const int i2 = lt >> 3;
                const int j2 = (lt & 7) * 2;
                if (i2 > k) {
                    float mu = MU[row*16+i2];
                    A[i2*17+j2]   = fmaf(-mu, A[k*17+j2],   A[i2*17+j2]);
                    A[i2*17+j2+1] = fmaf(-mu, A[k*17+j2+1], A[i2*17+j2+1]);
                    if ((lt & 7) == 0) rs[i2] = fmaf(-mu, rs[k], rs[i2]);
                }
            }
            __syncthreads();
        }
        for (int k = 15; k >= 0; --k) {
            if (lt == 0) QD[row*16+k] = rs[k] / A[k*17+k];
            __syncthreads();
            if (lt < k) rs[lt] = fmaf(-QD[row*16+k], A[lt*17+k], rs[lt]);
            __syncthreads();
        }
    }

    if (tid < 128) {
        const int row = tid >> 5;
        const int e = tid & 31;
        out[(r0+row)*TW + e] = (e < 16) ? XR[row*TW + 16 + e] : QD[row*16 + e - 16];
    }
}

extern "C" void kernel_launch(void* const* d_in, const int* in_sizes, int n_in,
                              void* d_out, int out_size, void* d_ws, size_t ws_size,
                              hipStream_t stream) {
    const float* x  = (const float*)d_in[0];
    const float* W1 = (const float*)d_in[1];
    const float* b1 = (const float*)d_in[2];
    const float* W2 = (const float*)d_in[3];
    const float* b2 = (const float*)d_in[4];
    const float* W3 = (const float*)d_in[5];
    float* out = (float*)d_out;
    float* ws = (float*)d_ws;

    float* s1g = ws;
    float* h1g = ws + (1u << 20);
    float* u2g = ws + 2u * (1u << 20);
    float* d2g = ws + 3u * (1u << 20);
    float* vg  = ws + 4u * (1u << 20);

    k1_fwd<<<2048, 512, 0, stream>>>(x, W1, b1, s1g, h1g);
    dim3 g2(64, 8);
    k2_z2<<<g2, 256, 0, stream>>>(h1g, W2, b2, W3, u2g, d2g);
    k3_v<<<g2, 256, 0, stream>>>(u2g, W2, vg);
    k4_main<<<512, 512, 0, stream>>>(x, W1, W2, s1g, d2g, vg, out);
}